// Round 19
// baseline (1052.677 us; speedup 1.0000x reference)
//
#include <hip/hip_runtime.h>
#include <math.h>

#define POFF 128
#define SPAN 768          // 16 sub-chunks x 48 samples per group
#define M15  1536         // circular window = 2*SPAN

// ---------------------------------------------------------------------------
// Phase 1: PCR spline solve (validated R15). Single sample-minz init.
// ---------------------------------------------------------------------------
__global__ void __launch_bounds__(256)
spline_setup(const float* __restrict__ delay_in,
             const float* __restrict__ raw,
             double* __restrict__ coef,
             int* __restrict__ minz,
             int nf) {
    __shared__ double xch[3 * 256];
    __shared__ double Aa[2][512], Ab[2][512], Ac[2][512];
    __shared__ double Ad0[2][512], Ad1[2][512], Ad2[2][512];

    const int tid = threadIdx.x;
    if (tid == 0) *minz = 0x7fffffff;

    #pragma unroll
    for (int b = 0; b < 2; ++b)
        for (int i = tid; i < 512; i += 256) {
            Aa[b][i] = 0.0; Ab[b][i] = 1.0; Ac[b][i] = 0.0;
            Ad0[b][i] = 0.0; Ad1[b][i] = 0.0; Ad2[b][i] = 0.0;
        }

    if (tid < nf) {
        double s0 = 1.0 / (1.0 + exp(-(double)raw[2 * tid + 0]));
        double s1 = 1.0 / (1.0 + exp(-(double)raw[2 * tid + 1]));
        double ss = s0 + s1;
        xch[0 * 256 + tid] = (double)delay_in[tid];
        xch[1 * 256 + tid] = s0 / ss;
        xch[2 * 256 + tid] = s1 / ss;
    }
    __syncthreads();

    if (tid < nf) {
        int i = tid;
        double hinv = (double)(nf - 1);
        Aa[0][POFF + i] = (i > 0) ? 1.0 : 0.0;
        Ac[0][POFF + i] = (i < nf - 1) ? 1.0 : 0.0;
        Ab[0][POFF + i] = (i == 0 || i == nf - 1) ? 2.0 : 4.0;
        #pragma unroll
        for (int ch = 0; ch < 3; ++ch) {
            const double* x = xch + ch * 256;
            double r = 0.0;
            if (i < nf - 1) r += 3.0 * hinv * (x[i + 1] - x[i]);
            if (i > 0)      r += 3.0 * hinv * (x[i] - x[i - 1]);
            if (ch == 0) Ad0[0][POFF + i] = r;
            else if (ch == 1) Ad1[0][POFF + i] = r;
            else Ad2[0][POFF + i] = r;
        }
    }
    __syncthreads();

    int cur = 0;
    for (int s = 1; s < nf; s <<= 1) {
        int nxt = cur ^ 1;
        int ic = POFF + tid, im = ic - s, ip = ic + s;
        double ai = Aa[cur][ic], bi = Ab[cur][ic], ci = Ac[cur][ic];
        double alpha = -ai / Ab[cur][im];
        double gamma = -ci / Ab[cur][ip];
        double na = alpha * Aa[cur][im];
        double nc = gamma * Ac[cur][ip];
        double nb = bi + alpha * Ac[cur][im] + gamma * Aa[cur][ip];
        double n0 = Ad0[cur][ic] + alpha * Ad0[cur][im] + gamma * Ad0[cur][ip];
        double n1 = Ad1[cur][ic] + alpha * Ad1[cur][im] + gamma * Ad1[cur][ip];
        double n2 = Ad2[cur][ic] + alpha * Ad2[cur][im] + gamma * Ad2[cur][ip];
        Aa[nxt][ic] = na; Ab[nxt][ic] = nb; Ac[nxt][ic] = nc;
        Ad0[nxt][ic] = n0; Ad1[nxt][ic] = n1; Ad2[nxt][ic] = n2;
        cur = nxt;
        __syncthreads();
    }

    int nint = nf - 1;
    double hinv = (double)(nf - 1);
    if (tid < nint) {
        int i = tid;
        double rbI = 1.0 / Ab[cur][POFF + i], rbI1 = 1.0 / Ab[cur][POFF + i + 1];
        #pragma unroll
        for (int ch = 0; ch < 3; ++ch) {
            double ki, ki1;
            if (ch == 0) { ki = Ad0[cur][POFF + i] * rbI; ki1 = Ad0[cur][POFF + i + 1] * rbI1; }
            else if (ch == 1) { ki = Ad1[cur][POFF + i] * rbI; ki1 = Ad1[cur][POFF + i + 1] * rbI1; }
            else { ki = Ad2[cur][POFF + i] * rbI; ki1 = Ad2[cur][POFF + i + 1] * rbI1; }
            const double* x = xch + ch * 256;
            double dx3 = 3.0 * (x[i + 1] - x[i]);
            double two_c   = (2.0 * dx3 * hinv - 4.0 * ki - 2.0 * ki1) * hinv;
            double three_d = (-2.0 * dx3 * hinv + 3.0 * (ki + ki1)) * hinv * hinv;
            double* C = coef + (size_t)(ch * nint + i) * 4;
            C[0] = x[i];
            C[1] = ki;
            C[2] = 0.5 * two_c;
            C[3] = three_d * (1.0 / 3.0);
        }
    }
}

// ---------------------------------------------------------------------------
// Phase 2: per-sample spline eval, PADDED layout: row r (64 wide) holds
// sub-chunk r = samples [48r, 48r+48) in lanes 0-47; lanes 48-63 zero-pad.
// Element = {g1, g2, g3, s3} with s3 = (t - z - 3) mod 1536 (window M15;
// slots 1536/1537 shadow 0/1 in the scan buffer). Global min z via one
// atomic per wave (pad/overrun lanes contribute INT_MAX).
// ---------------------------------------------------------------------------
__global__ void eval_kernel(const double* __restrict__ coef,
                            float4* __restrict__ gx,
                            int* __restrict__ minz,
                            int n, int nRowsTot, int nf) {
    int j = blockIdx.x * blockDim.x + threadIdx.x;
    if (j >= (nRowsTot << 6)) return;
    int r = j >> 6, i = j & 63;
    int t = r * 48 + i;
    bool valid = (i < 48) && (t < n);

    int z = 0x7fffffff;
    if (valid) {
        double u = (double)t / (double)(n - 1);
        double nfm1 = (double)(nf - 1);
        int idx = (int)(u * nfm1);
        if (idx > nf - 2) idx = nf - 2;
        if (idx < 0) idx = 0;
        double tknot = (double)idx / nfm1;
        if (u < tknot && idx > 0) {
            idx--; tknot = (double)idx / nfm1;
        } else {
            double tnext = (double)(idx + 1) / nfm1;
            if (u >= tnext && idx < nf - 2) { idx++; tknot = tnext; }
        }
        double f = u - tknot;

        int nint = nf - 1;
        const double* C0 = coef + (size_t)(0 * nint + idx) * 4;
        const double* C1 = coef + (size_t)(1 * nint + idx) * 4;
        const double* C2 = coef + (size_t)(2 * nint + idx) * 4;
        double dly = C0[0] + f * (C0[1] + f * (C0[2] + f * C0[3]));
        double b1d = C1[0] + f * (C1[1] + f * (C1[2] + f * C1[3]));
        double b2d = C2[0] + f * (C2[1] + f * (C2[2] + f * C2[3]));

        double zf = floor(dly);
        z = (int)zf;
        float alfa = (float)(dly - zf);
        float b1 = (float)b1d, b2 = (float)b2d;
        float g1 = b1 * (1.0f - alfa);
        float g2 = b1 * alfa + b2 * (1.0f - alfa);
        float g3 = b2 * alfa;

        int s3 = (t - z - 3 + 2 * M15) % M15;   // t-z-3 >= -306 => arg > 0
        gx[j] = make_float4(g1, g2, g3, __uint_as_float((unsigned int)s3));
    } else {
        gx[j] = make_float4(0.f, 0.f, 0.f, 0.f);
    }

    int wmin = z;
    #pragma unroll
    for (int o = 32; o > 0; o >>= 1) wmin = min(wmin, __shfl_down(wmin, o, 64));
    if ((threadIdx.x & 63) == 0) atomicMin(minz, wmin);
}

// ---------------------------------------------------------------------------
// Phase 3: producer/consumer, S=48 sub-chunks with DISTANCE-2 dependency
// pipelining. minz >= 95 => sub-chunk h's taps reach back >= 96 = 2*48, so
// h depends on h-2: history reads for c+2 issue right after c's write,
// giving ~2 bodies (~100cy) of cover for the ~120cy LDS round-trip.
// All addressing compile-time (R4/R12/R14/R16/R18 law): padded 64-wide ring
// rows; window M=1536=2*span so write addr = (g&1)*768 + c*48 + tid, and
// shadow writes occur only at the static (g even, c==0, tid<2) point.
// q-stream register pipeline lead 8 (qs[c&7], 16%8=0 wraps across groups);
// H pipeline lead 2 (h[c&1]). Producer: 12 y-offload stores + 16
// global_load_lds (group g+2, 4-deep ring) + counted vmcnt(28); loads stay
// in flight across the raw s_barrier (R11/R13-validated).
// ---------------------------------------------------------------------------
__global__ void __launch_bounds__(128, 1)
scan_kernel(const float4* __restrict__ gx,
            const int* __restrict__ minz,
            const float* __restrict__ exc,
            float* __restrict__ y,
            float* __restrict__ sink,
            int n, int burst) {
    __shared__ float buf[1544];          // 1536 circular + 2 shadow + dummies
    __shared__ float excl[2048];
    __shared__ float4 ring[4096];        // 4 slots x 16 rows x 64 f4 = 64 KB

    const int tid = threadIdx.x;
    for (int i = tid; i < 1544; i += 128) buf[i] = 0.0f;
    for (int i = tid; i < 2048; i += 128) excl[i] = (i < burst) ? exc[i] : 0.0f;

    int mz = __builtin_amdgcn_readfirstlane(*minz);
    const int nRows = (n + 47) / 48;
    const int nFull = n / SPAN;

#define GLL(gsrc, ldst)                                                       \
    __builtin_amdgcn_global_load_lds(                                         \
        (const __attribute__((address_space(1))) void*)(gsrc),                \
        (__attribute__((address_space(3))) void*)(ldst), 16, 0, 0)

    // ---------------- generic fallback (never taken: mz ~ 100 >= 95) -------
    if (mz < 95 || nFull < 3) {
        __syncthreads();
        if (tid < 64) {
            int Df = mz + 1;
            if (Df > 48) Df = 48;
            if (Df < 1) Df = 1;
            for (int base = 0; base < n; base += Df) {
                int t = base + tid;
                bool ok = (tid < Df) && (t < n);
                float4 q = make_float4(0.f, 0.f, 0.f, 0.f);
                if (ok) {
                    int r = (int)(((unsigned long long)t * 87382ull) >> 22);
                    int i = t - r * 48;
                    q = gx[(r << 6) + i];
                }
                unsigned u = __float_as_uint(q.w);
                float a3 = buf[u], a2 = buf[u + 1], a1 = buf[u + 2];
                float x = (t < burst) ? excl[t & 2047] : 0.0f;
                float y0 = fmaf(q.x, a1, x);
                y0 = fmaf(q.y, a2, y0);
                y0 = fmaf(q.z, a3, y0);
                if (ok) {
                    int w = t % M15;
                    buf[w] = y0;
                    if (w < 2) buf[M15 + w] = y0;
                    y[t] = y0;
                }
            }
        }
        return;
    }

    // ---------------- prologue: producer fills ring slots 0,1 --------------
    if (tid >= 64) {
        int lane = tid - 64;
        #pragma unroll
        for (int r = 0; r < 16; ++r)
            GLL(gx + (r << 6) + lane, &ring[(r << 6)]);
        #pragma unroll
        for (int r = 0; r < 16; ++r)
            GLL(gx + ((16 + r) << 6) + lane, &ring[1024 + (r << 6)]);
    }
    __syncthreads();   // full drain: groups 0,1 resident; buf/excl visible

    // consumer persistent pipelines (producer lanes hold garbage)
    float4 qs[8];
    float h1[2], h2[2], h3[2];
    const bool lane48 = (tid < 48);
    if (tid < 64) {
        #pragma unroll
        for (int i = 0; i < 8; ++i) qs[i] = ring[(i << 6) + tid];
        unsigned u0 = __float_as_uint(qs[0].w);
        h3[0] = buf[u0]; h2[0] = buf[u0 + 1]; h1[0] = buf[u0 + 2];
        unsigned u1 = __float_as_uint(qs[1].w);
        h3[1] = buf[u1]; h2[1] = buf[u1 + 1]; h1[1] = buf[u1 + 2];
    }

    for (int g = 0; g < nFull; ++g) {
        if (tid >= 64) {
            // ---------------- producer ----------------
            int lane = tid - 64;
            int prevw = ((g - 1) & 1) ? SPAN : 0;
            int prev = (g - 1) * SPAN;
            float vals[12];
            #pragma unroll
            for (int k = 0; k < 12; ++k)
                vals[k] = buf[prevw + (k << 6) + lane];
            #pragma unroll
            for (int k = 0; k < 12; ++k) {
                int off = (k << 6) + lane;
                float* dst = (g > 0) ? (y + prev + off) : (sink + off);
                *dst = vals[k];                    // exactly 12 stores
            }
            int pr = (g + 2) << 4;                 // first row of group g+2
            int slot = (g + 2) & 3;
            #pragma unroll
            for (int r = 0; r < 16; ++r)
                GLL(gx + ((pr + r) << 6) + lane, &ring[(slot << 10) + (r << 6)]);
            // counted wait: prev group's 28 ops drained (incl. g+1's loads)
            asm volatile("s_waitcnt vmcnt(28)" ::: "memory");
        } else {
            // ---------------- consumer: 16 pipelined sub-chunk bodies ------
            const float4* Rp  = ring + ((g & 3) << 10);
            const float4* RpN = ring + (((g + 1) & 3) << 10);
            int wbase = (g & 1) ? SPAN : 0;
            int gb = g * SPAN;
            bool wx = (gb < burst);                // uniform; first 3 groups
            bool gEven = ((g & 1) == 0);
            #pragma unroll
            for (int c = 0; c < 16; ++c) {
                // 1. compute body c (H(c) issued 2 bodies ago; q(c) 8 ago)
                float4 q = qs[c & 7];
                float x0 = 0.0f;
                if (wx) {
                    int t = gb + c * 48 + tid;
                    x0 = (t < burst) ? excl[t & 2047] : 0.0f;
                }
                float y0 = fmaf(q.x, h1[c & 1], x0);
                y0 = fmaf(q.y, h2[c & 1], y0);
                y0 = fmaf(q.z, h3[c & 1], y0);
                int w = wbase + c * 48 + tid;      // < 1536 for lanes < 48
                buf[lane48 ? w : 1538] = y0;
                if (c == 0) {
                    if (gEven && tid < 2) buf[M15 + tid] = y0;   // static shadow
                }
                // 2. issue H(c+2): depends on W(c) just written (dist-2 dep)
                unsigned u = __float_as_uint(qs[(c + 2) & 7].w);
                h3[c & 1] = buf[u];
                h2[c & 1] = buf[u + 1];
                h1[c & 1] = buf[u + 2];
                // 3. issue q(c+8) stream read (ring only; no buf alias)
                if (c < 8) qs[c & 7] = Rp[((c + 8) << 6) + tid];
                else       qs[c & 7] = RpN[((c - 8) << 6) + tid];
            }
        }
        // raw barrier: producer's g+2 loads stay in flight across it
        asm volatile("s_waitcnt lgkmcnt(0)" ::: "memory");
        __builtin_amdgcn_sched_barrier(0);
        __builtin_amdgcn_s_barrier();
        __builtin_amdgcn_sched_barrier(0);
    }

    __syncthreads();   // drain everything before epilogue

    if (tid >= 64) {
        // offload group nFull-1 (final in buf)
        int lane = tid - 64;
        int prev = (nFull - 1) * SPAN;
        int prevw = ((nFull - 1) & 1) ? SPAN : 0;
        #pragma unroll
        for (int k = 0; k < 12; ++k) {
            int off = (k << 6) + lane;
            y[prev + off] = buf[prevw + off];
        }
    } else {
        // tail rows [nFull*16, nRows): serial depth-1, compile-time layout
        int tb = nFull * SPAN;
        int wb0 = (nFull & 1) ? SPAN : 0;
        for (int r = nFull << 4; r < nRows; ++r) {
            int t = r * 48 + tid;
            bool ok = lane48 && (t < n);
            float4 q = gx[(r << 6) + tid];
            unsigned u = __float_as_uint(q.w);
            float a3 = buf[u], a2 = buf[u + 1], a1 = buf[u + 2];
            float x = (t < burst) ? excl[t & 2047] : 0.0f;
            float y0 = fmaf(q.x, a1, x);
            y0 = fmaf(q.y, a2, y0);
            y0 = fmaf(q.z, a3, y0);
            if (ok) {
                int w = wb0 + (t - tb);
                buf[w] = y0;
                if (w < 2) buf[M15 + w] = y0;
                y[t] = y0;
            }
        }
    }
#undef GLL
}

// ---------------------------------------------------------------------------
extern "C" void kernel_launch(void* const* d_in, const int* in_sizes, int n_in,
                              void* d_out, int out_size, void* d_ws, size_t ws_size,
                              hipStream_t stream) {
    const float* delay = (const float*)d_in[0];
    const float* raw   = (const float*)d_in[1];
    const float* exc   = (const float*)d_in[2];
    int nf = in_sizes[0];
    int burst = in_sizes[2];
    if (burst > 2048) burst = 2048;
    int n = out_size;
    int nRowsTot = (n + 47) / 48 + 48;   // +3 groups prefetch overshoot

    char* ws = (char*)d_ws;
    size_t coefBytes = (size_t)3 * (nf - 1) * 4 * sizeof(double);
    size_t off = (coefBytes + 255) & ~(size_t)255;
    double* coef = (double*)ws;
    int* minz = (int*)(ws + off);
    off += 256;
    float* sink = (float*)(ws + off);
    off += 4096;
    float4* gxa = (float4*)(ws + off);   // nRowsTot * 64 float4

    spline_setup<<<1, 256, 0, stream>>>(delay, raw, coef, minz, nf);
    int nTotPad = nRowsTot << 6;
    eval_kernel<<<(nTotPad + 255) / 256, 256, 0, stream>>>(coef, gxa, minz, n, nRowsTot, nf);
    scan_kernel<<<1, 128, 0, stream>>>(gxa, minz, exc, (float*)d_out, sink, n, burst);
}

// Round 20
// 147.976 us; speedup vs baseline: 7.1138x; 7.1138x over previous
//
#include <hip/hip_runtime.h>
#include <math.h>

#define POFF 128

// ---------------------------------------------------------------------------
// Phase 1: natural cubic spline coefficients, 3 channels, via PARALLEL
// CYCLIC REDUCTION (PCR). 256 threads, one equation per thread, 8 strides,
// guard-padded identity rows eliminate boundary branches. (Validated R15:
// replaced the 50us serial Thomas solve with ~2us.)
// ---------------------------------------------------------------------------
__global__ void __launch_bounds__(256)
spline_setup(const float* __restrict__ delay_in,
             const float* __restrict__ raw,
             double* __restrict__ coef,
             int* __restrict__ minz,
             int nf) {
    __shared__ double xch[3 * 256];
    __shared__ double Aa[2][512], Ab[2][512], Ac[2][512];
    __shared__ double Ad0[2][512], Ad1[2][512], Ad2[2][512];

    const int tid = threadIdx.x;
    if (tid == 0) *minz = 0x7fffffff;

    #pragma unroll
    for (int b = 0; b < 2; ++b)
        for (int i = tid; i < 512; i += 256) {
            Aa[b][i] = 0.0; Ab[b][i] = 1.0; Ac[b][i] = 0.0;
            Ad0[b][i] = 0.0; Ad1[b][i] = 0.0; Ad2[b][i] = 0.0;
        }

    if (tid < nf) {
        double s0 = 1.0 / (1.0 + exp(-(double)raw[2 * tid + 0]));
        double s1 = 1.0 / (1.0 + exp(-(double)raw[2 * tid + 1]));
        double ss = s0 + s1;
        xch[0 * 256 + tid] = (double)delay_in[tid];
        xch[1 * 256 + tid] = s0 / ss;
        xch[2 * 256 + tid] = s1 / ss;
    }
    __syncthreads();

    if (tid < nf) {
        int i = tid;
        double hinv = (double)(nf - 1);
        Aa[0][POFF + i] = (i > 0) ? 1.0 : 0.0;
        Ac[0][POFF + i] = (i < nf - 1) ? 1.0 : 0.0;
        Ab[0][POFF + i] = (i == 0 || i == nf - 1) ? 2.0 : 4.0;
        #pragma unroll
        for (int ch = 0; ch < 3; ++ch) {
            const double* x = xch + ch * 256;
            double r = 0.0;
            if (i < nf - 1) r += 3.0 * hinv * (x[i + 1] - x[i]);
            if (i > 0)      r += 3.0 * hinv * (x[i] - x[i - 1]);
            if (ch == 0) Ad0[0][POFF + i] = r;
            else if (ch == 1) Ad1[0][POFF + i] = r;
            else Ad2[0][POFF + i] = r;
        }
    }
    __syncthreads();

    int cur = 0;
    for (int s = 1; s < nf; s <<= 1) {
        int nxt = cur ^ 1;
        int ic = POFF + tid, im = ic - s, ip = ic + s;
        double ai = Aa[cur][ic], bi = Ab[cur][ic], ci = Ac[cur][ic];
        double alpha = -ai / Ab[cur][im];
        double gamma = -ci / Ab[cur][ip];
        double na = alpha * Aa[cur][im];
        double nc = gamma * Ac[cur][ip];
        double nb = bi + alpha * Ac[cur][im] + gamma * Aa[cur][ip];
        double n0 = Ad0[cur][ic] + alpha * Ad0[cur][im] + gamma * Ad0[cur][ip];
        double n1 = Ad1[cur][ic] + alpha * Ad1[cur][im] + gamma * Ad1[cur][ip];
        double n2 = Ad2[cur][ic] + alpha * Ad2[cur][im] + gamma * Ad2[cur][ip];
        Aa[nxt][ic] = na; Ab[nxt][ic] = nb; Ac[nxt][ic] = nc;
        Ad0[nxt][ic] = n0; Ad1[nxt][ic] = n1; Ad2[nxt][ic] = n2;
        cur = nxt;
        __syncthreads();
    }

    int nint = nf - 1;
    double hinv = (double)(nf - 1);
    if (tid < nint) {
        int i = tid;
        double rbI = 1.0 / Ab[cur][POFF + i], rbI1 = 1.0 / Ab[cur][POFF + i + 1];
        #pragma unroll
        for (int ch = 0; ch < 3; ++ch) {
            double ki, ki1;
            if (ch == 0) { ki = Ad0[cur][POFF + i] * rbI; ki1 = Ad0[cur][POFF + i + 1] * rbI1; }
            else if (ch == 1) { ki = Ad1[cur][POFF + i] * rbI; ki1 = Ad1[cur][POFF + i + 1] * rbI1; }
            else { ki = Ad2[cur][POFF + i] * rbI; ki1 = Ad2[cur][POFF + i + 1] * rbI1; }
            const double* x = xch + ch * 256;
            double dx3 = 3.0 * (x[i + 1] - x[i]);
            double two_c   = (2.0 * dx3 * hinv - 4.0 * ki - 2.0 * ki1) * hinv;
            double three_d = (-2.0 * dx3 * hinv + 3.0 * (ki + ki1)) * hinv * hinv;
            double* C = coef + (size_t)(ch * nint + i) * 4;
            C[0] = x[i];
            C[1] = ki;
            C[2] = 0.5 * two_c;
            C[3] = three_d * (1.0 / 3.0);
        }
    }
}

// ---------------------------------------------------------------------------
// Phase 2: per-sample spline eval -> {g1, g2, g3, s3} one float4.
// s3 = (t - z - 3) & 2047. Global min z via one atomic per wave.
// Pads [n, nTot) with zeros.
// ---------------------------------------------------------------------------
__global__ void eval_kernel(const double* __restrict__ coef,
                            float4* __restrict__ gx,
                            int* __restrict__ minz,
                            int n, int nTot, int nf) {
    int j = blockIdx.x * blockDim.x + threadIdx.x;
    if (j >= nTot) return;
    if (j >= n) { gx[j] = make_float4(0.f, 0.f, 0.f, 0.f); return; }

    double u = (double)j / (double)(n - 1);
    double nfm1 = (double)(nf - 1);
    int idx = (int)(u * nfm1);
    if (idx > nf - 2) idx = nf - 2;
    if (idx < 0) idx = 0;
    double tknot = (double)idx / nfm1;
    if (u < tknot && idx > 0) {
        idx--; tknot = (double)idx / nfm1;
    } else {
        double tnext = (double)(idx + 1) / nfm1;
        if (u >= tnext && idx < nf - 2) { idx++; tknot = tnext; }
    }
    double f = u - tknot;

    int nint = nf - 1;
    const double* C0 = coef + (size_t)(0 * nint + idx) * 4;
    const double* C1 = coef + (size_t)(1 * nint + idx) * 4;
    const double* C2 = coef + (size_t)(2 * nint + idx) * 4;
    double dly = C0[0] + f * (C0[1] + f * (C0[2] + f * C0[3]));
    double b1d = C1[0] + f * (C1[1] + f * (C1[2] + f * C1[3]));
    double b2d = C2[0] + f * (C2[1] + f * (C2[2] + f * C2[3]));

    double zf = floor(dly);
    int z = (int)zf;
    float alfa = (float)(dly - zf);
    float b1 = (float)b1d, b2 = (float)b2d;
    float g1 = b1 * (1.0f - alfa);
    float g2 = b1 * alfa + b2 * (1.0f - alfa);
    float g3 = b2 * alfa;

    int s3 = (j - z - 3) & 2047;
    gx[j] = make_float4(g1, g2, g3, __uint_as_float((unsigned int)s3));

    int wmin = z;
    #pragma unroll
    for (int o = 32; o > 0; o >>= 1) wmin = min(wmin, __shfl_down(wmin, o, 64));
    if ((threadIdx.x & 63) == 0) atomicMin(minz, wmin);
}

// ---------------------------------------------------------------------------
// Phase 3: producer/consumer, FIXED D=64 (validated R13/R15: 144cy/row =
// LDS round-trip floor; the serial-chain structural limit). Group = 16
// chunks = 1024 samples. Minimal row body: compile-time offsets only.
// Producer: 16 y-offload stores + 16 global_load_lds (group g+2, 4-deep
// ring) + counted vmcnt(32); loads stay in flight across the raw s_barrier.
// ---------------------------------------------------------------------------
__global__ void __launch_bounds__(128, 1)
scan_kernel(const float4* __restrict__ gx,
            const int* __restrict__ minz,
            const float* __restrict__ exc,
            float* __restrict__ y,
            float* __restrict__ sink,
            int n, int burst) {
    __shared__ float buf[2052];          // 2048 circular + 2 shadow + pad
    __shared__ float excl[2048];
    __shared__ float4 ring[4 * 1024];    // 4 group-slots x 16 chunks x 64 = 64 KB

    const int tid = threadIdx.x;
    for (int i = tid; i < 2052; i += 128) buf[i] = 0.0f;
    for (int i = tid; i < 2048; i += 128) excl[i] = (i < burst) ? exc[i] : 0.0f;

    int mz = __builtin_amdgcn_readfirstlane(*minz);
    const int nFull = n >> 10;

#define GLL(gsrc, ldst)                                                       \
    __builtin_amdgcn_global_load_lds(                                         \
        (const __attribute__((address_space(1))) void*)(gsrc),                \
        (__attribute__((address_space(3))) void*)(ldst), 16, 0, 0)

    // ---------------- fallback (never taken for this data: mz ~ 100) -------
    if (mz < 63 || nFull < 2) {
        __syncthreads();
        if (tid < 64) {
            int Df = mz + 1;
            if (Df > 64) Df = 64;
            if (Df < 1) Df = 1;
            for (int base = 0; base < n; base += Df) {
                int t = base + tid;
                bool ok = (tid < Df) && (t < n);
                float4 q = ok ? gx[t] : make_float4(0.f, 0.f, 0.f, 0.f);
                unsigned u = __float_as_uint(q.w);
                float a3 = buf[u], a2 = buf[u + 1], a1 = buf[u + 2];
                float x = (t < burst) ? excl[t & 2047] : 0.0f;
                float y0 = fmaf(q.x, a1, x);
                y0 = fmaf(q.y, a2, y0);
                y0 = fmaf(q.z, a3, y0);
                if (ok) {
                    int w = t & 2047;
                    buf[w] = y0;
                    if (w < 2) buf[2048 + w] = y0;
                    y[t] = y0;
                }
            }
        }
        return;
    }

    // ---------------- prologue: producer fills groups 0,1 ------------------
    if (tid >= 64) {
        int lane = tid - 64;
        #pragma unroll
        for (int c = 0; c < 16; ++c)
            GLL(gx + (c << 6) + lane, &ring[(c << 6)]);
        #pragma unroll
        for (int c = 0; c < 16; ++c)
            GLL(gx + 1024 + (c << 6) + lane, &ring[1024 + (c << 6)]);
    }
    __syncthreads();   // full drain: groups 0,1 resident; buf/excl visible

    for (int g = 0; g < nFull; ++g) {
        if (tid >= 64) {
            // ---------------- producer ----------------
            int lane = tid - 64;
            int prevw = ((g - 1) & 1) << 10;       // buf window of group g-1
            int prev = (g - 1) << 10;
            float vals[16];
            #pragma unroll
            for (int k = 0; k < 16; ++k)
                vals[k] = buf[prevw + (k << 6) + lane];
            #pragma unroll
            for (int k = 0; k < 16; ++k) {
                int off = (k << 6) + lane;
                float* dst = (g > 0) ? (y + prev + off) : (sink + off);
                *dst = vals[k];                    // exactly 16 stores
            }
            int pb = (g + 2) << 10;
            int slot = (g + 2) & 3;
            #pragma unroll
            for (int c = 0; c < 16; ++c)
                GLL(gx + pb + (c << 6) + lane, &ring[(slot << 10) + (c << 6)]);
            // counted wait: drains prev group's 32 ops (incl. g+1's loads)
            asm volatile("s_waitcnt vmcnt(32)" ::: "memory");
        } else {
            // ---------------- consumer (pure LDS) ----------------
            const float4* Rp = ring + ((g & 3) << 10);
            int wb = ((g & 1) << 10) + tid;        // buf write base (c=0)
            int gb = g << 10;
            bool wx = (gb < burst);                // uniform; first 2 groups
            float4 q = Rp[tid];
            #pragma unroll
            for (int c = 0; c < 16; ++c) {
                float4 qn;
                if (c < 15) qn = Rp[((c + 1) << 6) + tid];
                unsigned u = __float_as_uint(q.w);
                float a3 = buf[u], a2 = buf[u + 1], a1 = buf[u + 2];
                float x = 0.0f;
                if (wx) {
                    int t = gb + (c << 6) + tid;
                    x = (t < burst) ? excl[t & 2047] : 0.0f;
                }
                float y0 = fmaf(q.x, a1, x);
                y0 = fmaf(q.y, a2, y0);
                y0 = fmaf(q.z, a3, y0);
                buf[wb + (c << 6)] = y0;
                if (c == 0 && (g & 1) == 0 && tid < 2) buf[2048 + tid] = y0;
                q = qn;
            }
        }
        // raw barrier: producer's g+2 loads stay in flight across it
        asm volatile("s_waitcnt lgkmcnt(0)" ::: "memory");
        __builtin_amdgcn_sched_barrier(0);
        __builtin_amdgcn_s_barrier();
        __builtin_amdgcn_sched_barrier(0);
    }

    __syncthreads();   // drain everything before epilogue

    if (tid >= 64) {
        // offload group nFull-1 (final in buf)
        int lane = tid - 64;
        int start = (nFull - 1) << 10;
        #pragma unroll
        for (int k = 0; k < 16; ++k) {
            int t = start + (k << 6) + lane;
            if (t < n) y[t] = buf[t & 2047];
        }
    } else {
        // tail samples [nFull<<10, n): direct-global, masked (empty when 1024|n)
        for (int base = nFull << 10; base < n; base += 64) {
            int t = base + tid;
            bool ok = (t < n);
            float4 q = ok ? gx[t] : make_float4(0.f, 0.f, 0.f, 0.f);
            unsigned u = __float_as_uint(q.w);
            float a3 = buf[u], a2 = buf[u + 1], a1 = buf[u + 2];
            float x = (t < burst) ? excl[t & 2047] : 0.0f;
            float y0 = fmaf(q.x, a1, x);
            y0 = fmaf(q.y, a2, y0);
            y0 = fmaf(q.z, a3, y0);
            if (ok) {
                int w = t & 2047;
                buf[w] = y0;
                if (w < 2) buf[2048 + w] = y0;
                y[t] = y0;
            }
        }
    }
#undef GLL
}

// ---------------------------------------------------------------------------
extern "C" void kernel_launch(void* const* d_in, const int* in_sizes, int n_in,
                              void* d_out, int out_size, void* d_ws, size_t ws_size,
                              hipStream_t stream) {
    const float* delay = (const float*)d_in[0];
    const float* raw   = (const float*)d_in[1];
    const float* exc   = (const float*)d_in[2];
    int nf = in_sizes[0];
    int burst = in_sizes[2];
    if (burst > 2048) burst = 2048;
    int n = out_size;
    int nTot = n + 4096;   // pad covers producer prefetch overshoot (2 groups)

    char* ws = (char*)d_ws;
    size_t coefBytes = (size_t)3 * (nf - 1) * 4 * sizeof(double);
    size_t off = (coefBytes + 255) & ~(size_t)255;
    double* coef = (double*)ws;
    int* minz = (int*)(ws + off);
    off += 256;
    float* sink = (float*)(ws + off);
    off += 4096;
    float4* gxa = (float4*)(ws + off);

    spline_setup<<<1, 256, 0, stream>>>(delay, raw, coef, minz, nf);
    eval_kernel<<<(nTot + 255) / 256, 256, 0, stream>>>(coef, gxa, minz, n, nTot, nf);
    scan_kernel<<<1, 128, 0, stream>>>(gxa, minz, exc, (float*)d_out, sink, n, burst);
}